// Round 3
// baseline (241.356 us; speedup 1.0000x reference)
//
#include <hip/hip_runtime.h>
#include <math.h>

#define NQ 10
#define DIM 1024
#define NL 2

// ---------------------------------------------------------------------------
// Precompute the 20 Rot gate matrices into workspace.
// Per gate 8 floats: u00r,u00i,u01r,u01i,u10r,u10i,u11r,u11i
// Rot(phi,theta,omega) = RZ(omega) RY(theta) RZ(phi):
//   u00 = e^{-i(phi+omega)/2} cos(theta/2)
//   u01 = -e^{+i(phi-omega)/2} sin(theta/2)
//   u10 = e^{+i(omega-phi)/2} sin(theta/2)
//   u11 = e^{+i(phi+omega)/2} cos(theta/2)
// ---------------------------------------------------------------------------
__global__ void precompute_gates(const float* __restrict__ w, float* __restrict__ g) {
    int t = threadIdx.x;
    if (t < NL * NQ) {
        float phi = w[t * 3 + 0], theta = w[t * 3 + 1], omega = w[t * 3 + 2];
        float c  = cosf(0.5f * theta), s = sinf(0.5f * theta);
        float ap = 0.5f * phi, ao = 0.5f * omega;
        float cs = cosf(ap + ao), ss = sinf(ap + ao);
        float cd = cosf(ap - ao), sd = sinf(ap - ao);
        float* o = g + t * 8;
        o[0] =  c * cs;  o[1] = -c * ss;   // u00
        o[2] = -s * cd;  o[3] = -s * sd;   // u01
        o[4] =  s * cd;  o[5] = -s * sd;   // u10
        o[6] =  c * cs;  o[7] =  c * ss;   // u11
    }
}

__device__ __forceinline__ float shx(float v, int m) {
    return __shfl_xor(v, m, 64);
}

// ---------------------------------------------------------------------------
// Rot gate on bit position P (P = 9 - wire). Bits 0-3 in-register, 4-9 lane.
// ---------------------------------------------------------------------------
template<int P>
__device__ __forceinline__ void apply_rot(float (&re)[16], float (&im)[16],
                                          const float* __restrict__ g, int lane) {
    float u00r = g[0], u00i = g[1], u01r = g[2], u01i = g[3];
    float u10r = g[4], u10i = g[5], u11r = g[6], u11i = g[7];
    if constexpr (P <= 3) {
        constexpr int m = 1 << P;
        #pragma unroll
        for (int r = 0; r < 16; ++r) {
            if (!(r & m)) {
                const int r2 = r | m;
                float a0r = re[r], a0i = im[r], a1r = re[r2], a1i = im[r2];
                re[r]  = u00r * a0r - u00i * a0i + u01r * a1r - u01i * a1i;
                im[r]  = u00r * a0i + u00i * a0r + u01r * a1i + u01i * a1r;
                re[r2] = u10r * a0r - u10i * a0i + u11r * a1r - u11i * a1i;
                im[r2] = u10r * a0i + u10i * a0r + u11r * a1i + u11i * a1r;
            }
        }
    } else {
        constexpr int lm = 1 << (P - 4);
        const bool hi = (lane & lm) != 0;
        // out = A*mine + B*partner;  lo lane: A=u00,B=u01;  hi lane: A=u11,B=u10
        float Ar = hi ? u11r : u00r, Ai = hi ? u11i : u00i;
        float Br = hi ? u10r : u01r, Bi = hi ? u10i : u01i;
        #pragma unroll
        for (int r = 0; r < 16; ++r) {
            float pr = shx(re[r], lm), pi = shx(im[r], lm);
            float mr = re[r], mi = im[r];
            re[r] = Ar * mr - Ai * mi + Br * pr - Bi * pi;
            im[r] = Ar * mi + Ai * mr + Br * pi + Bi * pr;
        }
    }
}

// ---------------------------------------------------------------------------
// CNOT with control bit PC, target bit PT (bit positions, 9-wire convention).
// ---------------------------------------------------------------------------
template<int PC, int PT>
__device__ __forceinline__ void apply_cnot(float (&re)[16], float (&im)[16], int lane) {
    if constexpr (PC >= 4 && PT >= 4) {
        constexpr int lm = 1 << (PT - 4);
        const bool ctrl = (lane & (1 << (PC - 4))) != 0;
        #pragma unroll
        for (int r = 0; r < 16; ++r) {
            float pr = shx(re[r], lm), pi = shx(im[r], lm);
            re[r] = ctrl ? pr : re[r];
            im[r] = ctrl ? pi : im[r];
        }
    } else if constexpr (PC >= 4 && PT <= 3) {
        constexpr int m = 1 << PT;
        const bool ctrl = (lane & (1 << (PC - 4))) != 0;
        #pragma unroll
        for (int r = 0; r < 16; ++r) {
            if (!(r & m)) {
                const int r2 = r | m;
                float t0r = re[r], t0i = im[r], t1r = re[r2], t1i = im[r2];
                re[r]  = ctrl ? t1r : t0r;  im[r]  = ctrl ? t1i : t0i;
                re[r2] = ctrl ? t0r : t1r;  im[r2] = ctrl ? t0i : t1i;
            }
        }
    } else if constexpr (PC <= 3 && PT >= 4) {
        constexpr int lm = 1 << (PT - 4);
        constexpr int cm = 1 << PC;
        #pragma unroll
        for (int r = 0; r < 16; ++r) {
            if (r & cm) {   // compile-time predicate: branch is lane-uniform
                re[r] = shx(re[r], lm);
                im[r] = shx(im[r], lm);
            }
        }
    } else {
        constexpr int cm = 1 << PC, tm = 1 << PT;
        #pragma unroll
        for (int r = 0; r < 16; ++r) {
            if ((r & cm) && !(r & tm)) {
                const int r2 = r | tm;
                float tr = re[r]; re[r] = re[r2]; re[r2] = tr;
                float ti = im[r]; im[r] = im[r2]; im[r2] = ti;
            }
        }
    }
}

// ---------------------------------------------------------------------------
// Main kernel: one wave (64 lanes) per batch element; 4 waves per block.
// Amplitude k = (lane << 4) | r ; wire q <-> bit (9-q).
// ---------------------------------------------------------------------------
__global__ __launch_bounds__(256) void qsim(const float* __restrict__ x,
                                            const float* __restrict__ gates,
                                            float* __restrict__ out, int B) {
    const int lane = threadIdx.x & 63;
    const int wave = threadIdx.x >> 6;
    const int row  = blockIdx.x * 4 + wave;
    if (row >= B) return;

    const float* xr = x + (size_t)row * DIM + lane * 16;
    float re[16], im[16];
    {
        float4 v0 = *(const float4*)(xr + 0);
        float4 v1 = *(const float4*)(xr + 4);
        float4 v2 = *(const float4*)(xr + 8);
        float4 v3 = *(const float4*)(xr + 12);
        re[0]=v0.x; re[1]=v0.y; re[2]=v0.z; re[3]=v0.w;
        re[4]=v1.x; re[5]=v1.y; re[6]=v1.z; re[7]=v1.w;
        re[8]=v2.x; re[9]=v2.y; re[10]=v2.z; re[11]=v2.w;
        re[12]=v3.x; re[13]=v3.y; re[14]=v3.z; re[15]=v3.w;
    }
    float nrm = 0.f;
    #pragma unroll
    for (int r = 0; r < 16; ++r) nrm += re[r] * re[r];
    #pragma unroll
    for (int m = 1; m < 64; m <<= 1) nrm += shx(nrm, m);
    float inv = rsqrtf(nrm);
    #pragma unroll
    for (int r = 0; r < 16; ++r) { re[r] *= inv; im[r] = 0.f; }

    #define ROT(l, q) apply_rot<9 - (q)>(re, im, gates + ((l) * 10 + (q)) * 8, lane)

    // ----- layer 0: Rot all wires, then CNOT ring r=1 -----
    ROT(0,0); ROT(0,1); ROT(0,2); ROT(0,3); ROT(0,4);
    ROT(0,5); ROT(0,6); ROT(0,7); ROT(0,8); ROT(0,9);
    apply_cnot<9,8>(re,im,lane); apply_cnot<8,7>(re,im,lane);
    apply_cnot<7,6>(re,im,lane); apply_cnot<6,5>(re,im,lane);
    apply_cnot<5,4>(re,im,lane); apply_cnot<4,3>(re,im,lane);
    apply_cnot<3,2>(re,im,lane); apply_cnot<2,1>(re,im,lane);
    apply_cnot<1,0>(re,im,lane); apply_cnot<0,9>(re,im,lane);

    // ----- layer 1: Rot all wires, then CNOT ring r=2 -----
    ROT(1,0); ROT(1,1); ROT(1,2); ROT(1,3); ROT(1,4);
    ROT(1,5); ROT(1,6); ROT(1,7); ROT(1,8); ROT(1,9);
    apply_cnot<9,7>(re,im,lane); apply_cnot<8,6>(re,im,lane);
    apply_cnot<7,5>(re,im,lane); apply_cnot<6,4>(re,im,lane);
    apply_cnot<5,3>(re,im,lane); apply_cnot<4,2>(re,im,lane);
    apply_cnot<3,1>(re,im,lane); apply_cnot<2,0>(re,im,lane);
    apply_cnot<1,9>(re,im,lane); apply_cnot<0,8>(re,im,lane);

    #undef ROT

    // ----- probabilities and PauliZ expvals -----
    float p[16];
    #pragma unroll
    for (int r = 0; r < 16; ++r) p[r] = re[r] * re[r] + im[r] * im[r];
    float sum = 0.f;
    #pragma unroll
    for (int r = 0; r < 16; ++r) sum += p[r];

    float e[10];
    // qubits 6..9 live on register bits 3..0: e = sum - 2*sum_{bit=1}
    #pragma unroll
    for (int i = 6; i < 10; ++i) {
        const int m = 1 << (9 - i);
        float s1 = 0.f;
        #pragma unroll
        for (int r = 0; r < 16; ++r) if (r & m) s1 += p[r];
        e[i] = sum - 2.f * s1;
    }
    // qubits 0..5 live on lane bits 5..0: sign by lane bit
    #pragma unroll
    for (int i = 0; i < 6; ++i) {
        const int lm = 1 << (5 - i);
        e[i] = (lane & lm) ? -sum : sum;
    }
    // wave-wide butterfly reduce each expval
    #pragma unroll
    for (int i = 0; i < 10; ++i) {
        #pragma unroll
        for (int m = 1; m < 64; m <<= 1) e[i] += shx(e[i], m);
    }
    if (lane == 0) {
        float* o = out + (size_t)row * NQ;
        #pragma unroll
        for (int i = 0; i < 10; ++i) o[i] = e[i];
    }
}

extern "C" void kernel_launch(void* const* d_in, const int* in_sizes, int n_in,
                              void* d_out, int out_size, void* d_ws, size_t ws_size,
                              hipStream_t stream) {
    const float* x = (const float*)d_in[0];
    const float* w = (const float*)d_in[1];
    float* gates = (float*)d_ws;                  // 160 floats
    float* out = (float*)d_out;

    const int B = in_sizes[0] / DIM;              // 16384

    precompute_gates<<<1, 64, 0, stream>>>(w, gates);
    qsim<<<(B + 3) / 4, 256, 0, stream>>>(x, gates, out, B);
}

// Round 8
// 221.866 us; speedup vs baseline: 1.0878x; 1.0878x over previous
//
#include <hip/hip_runtime.h>
#include <math.h>

#define NQ 10
#define DIM 1024
#define NL 2

// ---------------------------------------------------------------------------
// Precompute the 20 Rot gate matrices into workspace.
// Per gate 8 floats: u00r,u00i,u01r,u01i,u10r,u10i,u11r,u11i
// Rot(phi,theta,omega) = RZ(omega) RY(theta) RZ(phi)
// ---------------------------------------------------------------------------
__global__ void precompute_gates(const float* __restrict__ w, float* __restrict__ g) {
    int t = threadIdx.x;
    if (t < NL * NQ) {
        float phi = w[t * 3 + 0], theta = w[t * 3 + 1], omega = w[t * 3 + 2];
        float c  = cosf(0.5f * theta), s = sinf(0.5f * theta);
        float ap = 0.5f * phi, ao = 0.5f * omega;
        float cs = cosf(ap + ao), ss = sinf(ap + ao);
        float cd = cosf(ap - ao), sd = sinf(ap - ao);
        float* o = g + t * 8;
        o[0] =  c * cs;  o[1] = -c * ss;   // u00
        o[2] = -s * cd;  o[3] = -s * sd;   // u01
        o[4] =  s * cd;  o[5] = -s * sd;   // u10
        o[6] =  c * cs;  o[7] =  c * ss;   // u11
    }
}

// ---------------------------------------------------------------------------
// Cross-lane primitives.
//   xor1  -> DPP quad_perm [1,0,3,2] = 0xB1           (VALU)
//   xor2  -> DPP quad_perm [2,3,0,1] = 0x4E           (VALU)
//   xor4  -> ds_swizzle BitMode xor=4 -> 0x101F       (DS)
//   xor8  -> DPP row_ror:8 = 0x128 ((l+8)%16 == l^8)  (VALU)
//   xor16 -> v_permlane16_swap_b32                    (VALU, gfx950)
//   xor32 -> v_permlane32_swap_b32                    (VALU, gfx950)
// permlaneN_swap(d,s) with d=s=v (distinct registers):
//   d' rows = {v.r0,v.r0,v.r2,v.r2}(16) / {v.lo,v.lo}(32)
//   s' rows = {v.r1,v.r1,v.r3,v.r3}(16) / {v.hi,v.hi}(32)
// => for (lane&LM)==0: mine=d', partner=s'; else mine=s', partner=d'.
// Butterfly sum is d'+s' with NO select.
// NOTE: the builtin (returns both results as uint2) is mandatory-preferred:
// naive asm("+v","+v") lets regalloc coalesce d and s (same value!) into ONE
// register -> self-swap garbage. That was the round-3->6 correctness bug.
// ---------------------------------------------------------------------------
template<int CTRL>
__device__ __forceinline__ float dppmov(float v) {
    return __int_as_float(
        __builtin_amdgcn_mov_dpp(__float_as_int(v), CTRL, 0xF, 0xF, true));
}

typedef unsigned u32x2 __attribute__((ext_vector_type(2)));

template<int LM>
__device__ __forceinline__ void plswap(float& d, float& s) {
#if __has_builtin(__builtin_amdgcn_permlane16_swap) && __has_builtin(__builtin_amdgcn_permlane32_swap)
    u32x2 r;
    if constexpr (LM == 16)
        r = __builtin_amdgcn_permlane16_swap(__float_as_uint(d), __float_as_uint(s), false, false);
    else
        r = __builtin_amdgcn_permlane32_swap(__float_as_uint(d), __float_as_uint(s), false, false);
    d = __uint_as_float(r.x);
    s = __uint_as_float(r.y);
#else
    // Opaque copy: s becomes an asm-defined value the compiler cannot prove
    // equal to d, forcing distinct physical registers for the swap.
    asm("v_mov_b32 %0, %1" : "=v"(s) : "v"(s));
    if constexpr (LM == 16) asm("v_permlane16_swap_b32 %0, %1" : "+v"(d), "+v"(s));
    else                    asm("v_permlane32_swap_b32 %0, %1" : "+v"(d), "+v"(s));
#endif
}

// partner value v[lane ^ LM], LM in {1,2,4,8}
template<int LM>
__device__ __forceinline__ float xfetch(float v) {
    if constexpr (LM == 1)      return dppmov<0xB1>(v);
    else if constexpr (LM == 2) return dppmov<0x4E>(v);
    else if constexpr (LM == 4)
        return __int_as_float(__builtin_amdgcn_ds_swizzle(__float_as_int(v), 0x101F));
    else                        return dppmov<0x128>(v);   // LM == 8
}

template<int LM>
__device__ __forceinline__ float bfly_add(float v) {
    if constexpr (LM >= 16) { float d = v, s = v; plswap<LM>(d, s); return d + s; }
    else                    return v + xfetch<LM>(v);
}

// ---------------------------------------------------------------------------
// Rot gate on bit position P (P = 9 - wire). Bits 0-3 in-register, 4-9 lane.
// ---------------------------------------------------------------------------
template<int P>
__device__ __forceinline__ void apply_rot(float (&re)[16], float (&im)[16],
                                          const float* __restrict__ g, int lane) {
    float u00r = g[0], u00i = g[1], u01r = g[2], u01i = g[3];
    float u10r = g[4], u10i = g[5], u11r = g[6], u11i = g[7];
    if constexpr (P <= 3) {
        constexpr int m = 1 << P;
        #pragma unroll
        for (int r = 0; r < 16; ++r) {
            if (!(r & m)) {
                const int r2 = r | m;
                float a0r = re[r], a0i = im[r], a1r = re[r2], a1i = im[r2];
                re[r]  = u00r * a0r - u00i * a0i + u01r * a1r - u01i * a1i;
                im[r]  = u00r * a0i + u00i * a0r + u01r * a1i + u01i * a1r;
                re[r2] = u10r * a0r - u10i * a0i + u11r * a1r - u11i * a1i;
                im[r2] = u10r * a0i + u10i * a0r + u11r * a1i + u11i * a1r;
            }
        }
    } else if constexpr (P <= 7) {
        constexpr int LM = 1 << (P - 4);           // 1,2,4,8
        const bool hi = (lane & LM) != 0;
        // out = A*mine + B*partner
        float Ar = hi ? u11r : u00r, Ai = hi ? u11i : u00i;
        float Br = hi ? u10r : u01r, Bi = hi ? u10i : u01i;
        #pragma unroll
        for (int r = 0; r < 16; ++r) {
            float pr = xfetch<LM>(re[r]), pi = xfetch<LM>(im[r]);
            float mr = re[r], mi = im[r];
            re[r] = Ar * mr - Ai * mi + Br * pr - Bi * pi;
            im[r] = Ar * mi + Ai * mr + Br * pi + Bi * pr;
        }
    } else {
        constexpr int LM = 1 << (P - 4);           // 16 or 32
        const bool hi = (lane & LM) != 0;
        // out = Cd*d' + Cs*s'  (selection folded into coefficients, hoisted)
        // lo lane: out = u00*mine(d') + u01*partner(s')
        // hi lane: out = u11*mine(s') + u10*partner(d')
        float Cdr = hi ? u10r : u00r, Cdi = hi ? u10i : u00i;
        float Csr = hi ? u11r : u01r, Csi = hi ? u11i : u01i;
        #pragma unroll
        for (int r = 0; r < 16; ++r) {
            float dr = re[r], sr = re[r]; plswap<LM>(dr, sr);
            float di = im[r], si = im[r]; plswap<LM>(di, si);
            re[r] = Cdr * dr - Cdi * di + Csr * sr - Csi * si;
            im[r] = Cdr * di + Cdi * dr + Csr * si + Csi * sr;
        }
    }
}

// ---------------------------------------------------------------------------
// CNOT with control bit PC, target bit PT.
// ---------------------------------------------------------------------------
template<int PC, int PT>
__device__ __forceinline__ void apply_cnot(float (&re)[16], float (&im)[16], int lane) {
    if constexpr (PC >= 4 && PT >= 4) {
        constexpr int LM = 1 << (PT - 4);
        const bool ctrl = (lane & (1 << (PC - 4))) != 0;
        if constexpr (LM >= 16) {
            const bool t = (lane & LM) != 0;
            const bool sel = (ctrl == t);          // out = sel ? d' : s'
            #pragma unroll
            for (int r = 0; r < 16; ++r) {
                float dr = re[r], sr = re[r]; plswap<LM>(dr, sr);
                float di = im[r], si = im[r]; plswap<LM>(di, si);
                re[r] = sel ? dr : sr;
                im[r] = sel ? di : si;
            }
        } else {
            #pragma unroll
            for (int r = 0; r < 16; ++r) {
                float pr = xfetch<LM>(re[r]), pi = xfetch<LM>(im[r]);
                re[r] = ctrl ? pr : re[r];
                im[r] = ctrl ? pi : im[r];
            }
        }
    } else if constexpr (PC >= 4 && PT <= 3) {
        constexpr int m = 1 << PT;
        const bool ctrl = (lane & (1 << (PC - 4))) != 0;
        #pragma unroll
        for (int r = 0; r < 16; ++r) {
            if (!(r & m)) {
                const int r2 = r | m;
                float t0r = re[r], t0i = im[r], t1r = re[r2], t1i = im[r2];
                re[r]  = ctrl ? t1r : t0r;  im[r]  = ctrl ? t1i : t0i;
                re[r2] = ctrl ? t0r : t1r;  im[r2] = ctrl ? t0i : t1i;
            }
        }
    } else if constexpr (PC <= 3 && PT >= 4) {
        constexpr int LM = 1 << (PT - 4);
        constexpr int cm = 1 << PC;
        if constexpr (LM >= 16) {
            const bool t = (lane & LM) != 0;       // partner = t ? d' : s'
            #pragma unroll
            for (int r = 0; r < 16; ++r) {
                if (r & cm) {
                    float dr = re[r], sr = re[r]; plswap<LM>(dr, sr);
                    float di = im[r], si = im[r]; plswap<LM>(di, si);
                    re[r] = t ? dr : sr;
                    im[r] = t ? di : si;
                }
            }
        } else {
            #pragma unroll
            for (int r = 0; r < 16; ++r) {
                if (r & cm) {                      // compile-time, lane-uniform
                    re[r] = xfetch<LM>(re[r]);
                    im[r] = xfetch<LM>(im[r]);
                }
            }
        }
    } else {
        constexpr int cm = 1 << PC, tm = 1 << PT;
        #pragma unroll
        for (int r = 0; r < 16; ++r) {
            if ((r & cm) && !(r & tm)) {
                const int r2 = r | tm;
                float tr = re[r]; re[r] = re[r2]; re[r2] = tr;
                float ti = im[r]; im[r] = im[r2]; im[r2] = ti;
            }
        }
    }
}

// ---------------------------------------------------------------------------
// Main kernel: one wave per batch element; 4 waves per block.
// Amplitude k = (lane << 4) | r ; wire q <-> bit (9-q).
// ---------------------------------------------------------------------------
__global__ __launch_bounds__(256) void qsim(const float* __restrict__ x,
                                            const float* __restrict__ gates,
                                            float* __restrict__ out, int B) {
    const int lane = threadIdx.x & 63;
    const int wave = threadIdx.x >> 6;
    const int row  = blockIdx.x * 4 + wave;
    if (row >= B) return;

    const float* xr = x + (size_t)row * DIM + lane * 16;
    float re[16], im[16];
    {
        float4 v0 = *(const float4*)(xr + 0);
        float4 v1 = *(const float4*)(xr + 4);
        float4 v2 = *(const float4*)(xr + 8);
        float4 v3 = *(const float4*)(xr + 12);
        re[0]=v0.x; re[1]=v0.y; re[2]=v0.z; re[3]=v0.w;
        re[4]=v1.x; re[5]=v1.y; re[6]=v1.z; re[7]=v1.w;
        re[8]=v2.x; re[9]=v2.y; re[10]=v2.z; re[11]=v2.w;
        re[12]=v3.x; re[13]=v3.y; re[14]=v3.z; re[15]=v3.w;
    }
    float nrm = 0.f;
    #pragma unroll
    for (int r = 0; r < 16; ++r) nrm += re[r] * re[r];
    nrm = bfly_add<1>(nrm); nrm = bfly_add<2>(nrm); nrm = bfly_add<4>(nrm);
    nrm = bfly_add<8>(nrm); nrm = bfly_add<16>(nrm); nrm = bfly_add<32>(nrm);
    float inv = rsqrtf(nrm);
    #pragma unroll
    for (int r = 0; r < 16; ++r) { re[r] *= inv; im[r] = 0.f; }

    #define ROT(l, q) apply_rot<9 - (q)>(re, im, gates + ((l) * 10 + (q)) * 8, lane)

    // ----- layer 0: Rot all wires, then CNOT ring r=1 -----
    ROT(0,0); ROT(0,1); ROT(0,2); ROT(0,3); ROT(0,4);
    ROT(0,5); ROT(0,6); ROT(0,7); ROT(0,8); ROT(0,9);
    apply_cnot<9,8>(re,im,lane); apply_cnot<8,7>(re,im,lane);
    apply_cnot<7,6>(re,im,lane); apply_cnot<6,5>(re,im,lane);
    apply_cnot<5,4>(re,im,lane); apply_cnot<4,3>(re,im,lane);
    apply_cnot<3,2>(re,im,lane); apply_cnot<2,1>(re,im,lane);
    apply_cnot<1,0>(re,im,lane); apply_cnot<0,9>(re,im,lane);

    // ----- layer 1: Rot all wires, then CNOT ring r=2 -----
    ROT(1,0); ROT(1,1); ROT(1,2); ROT(1,3); ROT(1,4);
    ROT(1,5); ROT(1,6); ROT(1,7); ROT(1,8); ROT(1,9);
    apply_cnot<9,7>(re,im,lane); apply_cnot<8,6>(re,im,lane);
    apply_cnot<7,5>(re,im,lane); apply_cnot<6,4>(re,im,lane);
    apply_cnot<5,3>(re,im,lane); apply_cnot<4,2>(re,im,lane);
    apply_cnot<3,1>(re,im,lane); apply_cnot<2,0>(re,im,lane);
    apply_cnot<1,9>(re,im,lane); apply_cnot<0,8>(re,im,lane);

    #undef ROT

    // ----- probabilities and PauliZ expvals -----
    float p[16];
    #pragma unroll
    for (int r = 0; r < 16; ++r) p[r] = re[r] * re[r] + im[r] * im[r];
    float sum = 0.f;
    #pragma unroll
    for (int r = 0; r < 16; ++r) sum += p[r];

    float e[10];
    // qubits 6..9 live on register bits 3..0: e = sum - 2*sum_{bit=1}
    #pragma unroll
    for (int i = 6; i < 10; ++i) {
        const int m = 1 << (9 - i);
        float s1 = 0.f;
        #pragma unroll
        for (int r = 0; r < 16; ++r) if (r & m) s1 += p[r];
        e[i] = sum - 2.f * s1;
    }
    // qubits 0..5 live on lane bits 5..0: sign by lane bit
    #pragma unroll
    for (int i = 0; i < 6; ++i) {
        const int lm = 1 << (5 - i);
        e[i] = (lane & lm) ? -sum : sum;
    }
    // wave-wide butterfly reduce each expval
    #pragma unroll
    for (int i = 0; i < 10; ++i) {
        e[i] = bfly_add<1>(e[i]);  e[i] = bfly_add<2>(e[i]);
        e[i] = bfly_add<4>(e[i]);  e[i] = bfly_add<8>(e[i]);
        e[i] = bfly_add<16>(e[i]); e[i] = bfly_add<32>(e[i]);
    }
    if (lane == 0) {
        float* o = out + (size_t)row * NQ;
        #pragma unroll
        for (int i = 0; i < 10; ++i) o[i] = e[i];
    }
}

extern "C" void kernel_launch(void* const* d_in, const int* in_sizes, int n_in,
                              void* d_out, int out_size, void* d_ws, size_t ws_size,
                              hipStream_t stream) {
    const float* x = (const float*)d_in[0];
    const float* w = (const float*)d_in[1];
    float* gates = (float*)d_ws;                  // 160 floats
    float* out = (float*)d_out;

    const int B = in_sizes[0] / DIM;              // 16384

    precompute_gates<<<1, 64, 0, stream>>>(w, gates);
    qsim<<<(B + 3) / 4, 256, 0, stream>>>(x, gates, out, B);
}